// Round 1
// baseline (3806.925 us; speedup 1.0000x reference)
//
#include <hip/hip_runtime.h>
#include <math.h>

#define NN   100000
#define EE   1600000
#define FIN  256
#define NH   8
#define C1D  8
#define H1DIM 64     // NH*C1D
#define NCLS 16
#define NEG  0.2f

#define NEDGE (EE + NN)   // with self-loops

// ---- workspace layout (float offsets) ----
#define OFF_M1    0                          // [NN*8]  uint-encoded max
#define OFF_DEN1  (OFF_M1   + NN*8)          // [NN*8]
#define OFF_ACC1  (OFF_DEN1 + NN*8)          // [NN*64] -> becomes h1 (elu'd)
#define OFF_M2    (OFF_ACC1 + NN*64)         // [NN]
#define OFF_DEN2  (OFF_M2   + NN)            // [NN]
#define OFF_ACC2  (OFF_DEN2 + NN)            // [NN*16]
#define ZERO_FLOATS (OFF_ACC2 + NN*16)       // everything above must be zeroed
#define OFF_H1LIN (ZERO_FLOATS)              // [NN*64]
#define OFF_AL1S  (OFF_H1LIN + NN*64)        // [NN*8]
#define OFF_AL1D  (OFF_AL1S + NN*8)          // [NN*8]
#define OFF_H2    (OFF_AL1D + NN*8)          // [NN*16]
#define OFF_AL2S  (OFF_H2   + NN*16)         // [NN]
#define OFF_AL2D  (OFF_AL2S + NN)            // [NN]

__device__ __forceinline__ unsigned enc_f32(float x) {
    unsigned u = __float_as_uint(x);
    return (u & 0x80000000u) ? ~u : (u | 0x80000000u);
}
__device__ __forceinline__ float dec_f32(unsigned u) {
    unsigned v = (u & 0x80000000u) ? (u & 0x7FFFFFFFu) : ~u;
    return __uint_as_float(v);
}
__device__ __forceinline__ float lrelu(float x) { return x >= 0.f ? x : NEG * x; }

// ---------- layer 1 GEMM: h1lin = x @ W1, al1s/al1d per-head logits ----------
__global__ __launch_bounds__(256) void k_gemm1(
    const float* __restrict__ x, const float* __restrict__ W1,
    const float* __restrict__ a1s, const float* __restrict__ a1d,
    float* __restrict__ h1lin, float* __restrict__ al1s, float* __restrict__ al1d)
{
    __shared__ float sW[128 * 64];   // 32 KB chunk of W1
    __shared__ float sx[4][256];     // 4 x-rows
    const int t = threadIdx.x;
    const int nodeBase = blockIdx.x * 4;

    for (int i = t; i < 4 * 256; i += 256) {
        int r = i >> 8, k = i & 255;
        int n = nodeBase + r;
        sx[r][k] = (n < NN) ? x[(size_t)n * FIN + k] : 0.f;
    }

    const int wv = t >> 6;   // node-in-block (one wave per node)
    const int c  = t & 63;   // output column
    float acc = 0.f;
    for (int ch = 0; ch < 2; ++ch) {
        __syncthreads();
        for (int i = t; i < 128 * 64; i += 256)
            sW[i] = W1[ch * 128 * 64 + i];
        __syncthreads();
        #pragma unroll 8
        for (int k = 0; k < 128; ++k)
            acc += sx[wv][ch * 128 + k] * sW[k * 64 + c];
    }

    const int n = nodeBase + wv;
    if (n >= NN) return;
    h1lin[(size_t)n * 64 + c] = acc;

    const int h = c >> 3, cc = c & 7;
    float vs = acc * a1s[h * 8 + cc];
    float vd = acc * a1d[h * 8 + cc];
    #pragma unroll
    for (int off = 1; off < 8; off <<= 1) {
        vs += __shfl_xor(vs, off, 64);
        vd += __shfl_xor(vd, off, 64);
    }
    if (cc == 0) { al1s[n * 8 + h] = vs; al1d[n * 8 + h] = vd; }
}

// ---------- layer 1 edge max ----------
__global__ __launch_bounds__(256) void k_edge_max1(
    const int* __restrict__ esrc, const int* __restrict__ edst,
    const float* __restrict__ al1s, const float* __restrict__ al1d,
    unsigned* __restrict__ m1)
{
    int tid = blockIdx.x * 256 + threadIdx.x;
    if (tid >= NEDGE * 8) return;
    const int h = tid & 7, ei = tid >> 3;
    int s, d;
    if (ei < EE) { s = esrc[ei]; d = edst[ei]; } else { s = d = ei - EE; }
    float e = lrelu(al1s[s * 8 + h] + al1d[d * 8 + h]);
    atomicMax(&m1[d * 8 + h], enc_f32(e));
}

// ---------- layer 1 edge weighted sum (unnormalized) ----------
__global__ __launch_bounds__(256) void k_edge_sum1(
    const int* __restrict__ esrc, const int* __restrict__ edst,
    const float* __restrict__ al1s, const float* __restrict__ al1d,
    const unsigned* __restrict__ m1, const float* __restrict__ h1lin,
    float* __restrict__ den1, float* __restrict__ acc1)
{
    int tid = blockIdx.x * 256 + threadIdx.x;
    if (tid >= NEDGE * 8) return;
    const int h = tid & 7, ei = tid >> 3;
    int s, d;
    if (ei < EE) { s = esrc[ei]; d = edst[ei]; } else { s = d = ei - EE; }
    float e = lrelu(al1s[s * 8 + h] + al1d[d * 8 + h]);
    float w = __expf(e - dec_f32(m1[d * 8 + h]));
    unsafeAtomicAdd(&den1[d * 8 + h], w);
    const float4* hp = (const float4*)(h1lin + (size_t)s * 64 + h * 8);
    float4 p0 = hp[0], p1 = hp[1];
    float* ap = acc1 + (size_t)d * 64 + h * 8;
    unsafeAtomicAdd(ap + 0, p0.x * w);
    unsafeAtomicAdd(ap + 1, p0.y * w);
    unsafeAtomicAdd(ap + 2, p0.z * w);
    unsafeAtomicAdd(ap + 3, p0.w * w);
    unsafeAtomicAdd(ap + 4, p1.x * w);
    unsafeAtomicAdd(ap + 5, p1.y * w);
    unsafeAtomicAdd(ap + 6, p1.z * w);
    unsafeAtomicAdd(ap + 7, p1.w * w);
}

// ---------- layer 1 finalize: divide, +b1, ELU (in place: acc1 -> h1) ----------
__global__ __launch_bounds__(256) void k_fin1(
    const float* __restrict__ den1, const float* __restrict__ b1,
    float* __restrict__ acc1)
{
    int t = blockIdx.x * 256 + threadIdx.x;
    if (t >= NN * 64) return;
    const int c = t & 63, n = t >> 6, h = c >> 3;
    float v = acc1[t] / den1[n * 8 + h] + b1[c];
    v = v > 0.f ? v : __expf(v) - 1.f;
    acc1[t] = v;
}

// ---------- layer 2 GEMM: h2 = h1 @ W2, al2s/al2d logits ----------
__global__ __launch_bounds__(256) void k_gemm2(
    const float* __restrict__ h1, const float* __restrict__ W2,
    const float* __restrict__ a2s, const float* __restrict__ a2d,
    float* __restrict__ h2, float* __restrict__ al2s, float* __restrict__ al2d)
{
    __shared__ float sW[64 * 16];
    const int t = threadIdx.x;
    for (int i = t; i < 64 * 16; i += 256) sW[i] = W2[i];
    __syncthreads();
    const int n = blockIdx.x * 16 + (t >> 4);
    const int k = t & 15;
    if (n >= NN) return;
    const float* hr = h1 + (size_t)n * 64;
    float acc = 0.f;
    #pragma unroll
    for (int c = 0; c < 64; ++c) acc += hr[c] * sW[c * 16 + k];
    h2[(size_t)n * 16 + k] = acc;
    float vs = acc * a2s[k], vd = acc * a2d[k];
    #pragma unroll
    for (int off = 1; off < 16; off <<= 1) {
        vs += __shfl_xor(vs, off, 64);
        vd += __shfl_xor(vd, off, 64);
    }
    if (k == 0) { al2s[n] = vs; al2d[n] = vd; }
}

// ---------- layer 2 edge max ----------
__global__ __launch_bounds__(256) void k_edge_max2(
    const int* __restrict__ esrc, const int* __restrict__ edst,
    const float* __restrict__ al2s, const float* __restrict__ al2d,
    unsigned* __restrict__ m2)
{
    int ei = blockIdx.x * 256 + threadIdx.x;
    if (ei >= NEDGE) return;
    int s, d;
    if (ei < EE) { s = esrc[ei]; d = edst[ei]; } else { s = d = ei - EE; }
    float e = lrelu(al2s[s] + al2d[d]);
    atomicMax(&m2[d], enc_f32(e));
}

// ---------- layer 2 edge weighted sum ----------
__global__ __launch_bounds__(256) void k_edge_sum2(
    const int* __restrict__ esrc, const int* __restrict__ edst,
    const float* __restrict__ al2s, const float* __restrict__ al2d,
    const unsigned* __restrict__ m2, const float* __restrict__ h2,
    float* __restrict__ den2, float* __restrict__ acc2)
{
    int tid = blockIdx.x * 256 + threadIdx.x;
    if (tid >= NEDGE * 16) return;
    const int k = tid & 15, ei = tid >> 4;
    int s, d;
    if (ei < EE) { s = esrc[ei]; d = edst[ei]; } else { s = d = ei - EE; }
    float e = lrelu(al2s[s] + al2d[d]);
    float w = __expf(e - dec_f32(m2[d]));
    unsafeAtomicAdd(&acc2[d * 16 + k], h2[(size_t)s * 16 + k] * w);
    if (k == 0) unsafeAtomicAdd(&den2[d], w);
}

// ---------- layer 2 finalize: divide, +b2, log_softmax ----------
__global__ __launch_bounds__(256) void k_fin2(
    const float* __restrict__ acc2, const float* __restrict__ den2,
    const float* __restrict__ b2, float* __restrict__ out)
{
    int n = blockIdx.x * 256 + threadIdx.x;
    if (n >= NN) return;
    float inv = 1.f / den2[n];
    float v[16];
    float mx = -1e30f;
    #pragma unroll
    for (int k = 0; k < 16; ++k) {
        v[k] = acc2[(size_t)n * 16 + k] * inv + b2[k];
        mx = fmaxf(mx, v[k]);
    }
    float sum = 0.f;
    #pragma unroll
    for (int k = 0; k < 16; ++k) sum += __expf(v[k] - mx);
    float ls = mx + logf(sum);
    #pragma unroll
    for (int k = 0; k < 16; ++k) out[(size_t)n * 16 + k] = v[k] - ls;
}

extern "C" void kernel_launch(void* const* d_in, const int* in_sizes, int n_in,
                              void* d_out, int out_size, void* d_ws, size_t ws_size,
                              hipStream_t stream)
{
    const float* x    = (const float*)d_in[0];
    const int*   eidx = (const int*)d_in[1];
    const float* W1   = (const float*)d_in[2];
    const float* a1s  = (const float*)d_in[3];
    const float* a1d  = (const float*)d_in[4];
    const float* b1   = (const float*)d_in[5];
    const float* W2   = (const float*)d_in[6];
    const float* a2s  = (const float*)d_in[7];
    const float* a2d  = (const float*)d_in[8];
    const float* b2   = (const float*)d_in[9];
    float* out = (float*)d_out;
    float* ws  = (float*)d_ws;

    const int* esrc = eidx;
    const int* edst = eidx + EE;

    unsigned* m1  = (unsigned*)(ws + OFF_M1);
    float* den1   = ws + OFF_DEN1;
    float* acc1   = ws + OFF_ACC1;   // becomes h1 after k_fin1
    unsigned* m2  = (unsigned*)(ws + OFF_M2);
    float* den2   = ws + OFF_DEN2;
    float* acc2   = ws + OFF_ACC2;
    float* h1lin  = ws + OFF_H1LIN;
    float* al1s   = ws + OFF_AL1S;
    float* al1d   = ws + OFF_AL1D;
    float* h2     = ws + OFF_H2;
    float* al2s   = ws + OFF_AL2S;
    float* al2d   = ws + OFF_AL2D;

    hipMemsetAsync(ws, 0, (size_t)ZERO_FLOATS * sizeof(float), stream);

    k_gemm1<<<NN / 4, 256, 0, stream>>>(x, W1, a1s, a1d, h1lin, al1s, al1d);

    int g_em1 = (NEDGE * 8 + 255) / 256;
    k_edge_max1<<<g_em1, 256, 0, stream>>>(esrc, edst, al1s, al1d, m1);
    k_edge_sum1<<<g_em1, 256, 0, stream>>>(esrc, edst, al1s, al1d, m1, h1lin, den1, acc1);

    k_fin1<<<(NN * 64) / 256, 256, 0, stream>>>(den1, b1, acc1);

    k_gemm2<<<NN / 16, 256, 0, stream>>>(acc1, W2, a2s, a2d, h2, al2s, al2d);

    k_edge_max2<<<(NEDGE + 255) / 256, 256, 0, stream>>>(esrc, edst, al2s, al2d, m2);
    k_edge_sum2<<<(NEDGE * 16 + 255) / 256, 256, 0, stream>>>(esrc, edst, al2s, al2d, m2, h2, den2, acc2);

    k_fin2<<<(NN + 255) / 256, 256, 0, stream>>>(acc2, den2, b2, out);
}

// Round 2
// 722.185 us; speedup vs baseline: 5.2714x; 5.2714x over previous
//
#include <hip/hip_runtime.h>
#include <math.h>

#define NN   100000
#define EE   1600000
#define FIN  256
#define NH   8
#define C1D  8
#define NCLS 16
#define NEG  0.2f

#define NEDGE (EE + NN)   // with self-loops
#define NBLK  ((NN + 255) / 256)   // 391 scan blocks

// ---- workspace layout (4-byte element offsets) ----
#define OFF_DEG   0                    // [NN] int, zeroed
#define OFF_CNT   (NN)                 // [NN] int, zeroed
#define NZERO_I   (2*NN)
#define OFF_ROW   (2*NN)               // [NN+1] int
#define OFF_TMP   (3*NN + 4)           // [NN] int
#define OFF_BSUM  (4*NN + 8)           // [512] int
#define OFF_ADJ   (4*NN + 520)         // [NEDGE] int (src per slot, CSR by dst)
#define OFF_H1LIN (OFF_ADJ + NEDGE)    // [NN*64]
#define OFF_AL1S  (OFF_H1LIN + NN*64)  // [NN*8]
#define OFF_AL1D  (OFF_AL1S + NN*8)    // [NN*8]
#define OFF_H1    (OFF_AL1D + NN*8)    // [NN*64]
#define OFF_H2    (OFF_H1 + NN*64)     // [NN*16]
#define OFF_AL2S  (OFF_H2 + NN*16)     // [NN]
#define OFF_AL2D  (OFF_AL2S + NN)      // [NN]

__device__ __forceinline__ float lrelu(float x) { return x >= 0.f ? x : NEG * x; }

// ---------- CSR build ----------
__global__ __launch_bounds__(256) void k_hist(
    const int* __restrict__ edst, int* __restrict__ deg)
{
    int ei = blockIdx.x * 256 + threadIdx.x;
    if (ei >= NEDGE) return;
    int d = (ei < EE) ? edst[ei] : ei - EE;
    atomicAdd(&deg[d], 1);
}

__global__ __launch_bounds__(256) void k_scan1(
    const int* __restrict__ deg, int* __restrict__ tmp, int* __restrict__ bsum)
{
    __shared__ int s[256];
    int t = threadIdx.x;
    int i = blockIdx.x * 256 + t;
    int v = (i < NN) ? deg[i] : 0;
    s[t] = v;
    __syncthreads();
    for (int off = 1; off < 256; off <<= 1) {
        int u = (t >= off) ? s[t - off] : 0;
        __syncthreads();
        s[t] += u;
        __syncthreads();
    }
    if (i < NN) tmp[i] = s[t] - v;          // exclusive within block
    if (t == 255) bsum[blockIdx.x] = s[255]; // block total
}

__global__ __launch_bounds__(512) void k_scan2(int* __restrict__ bsum)
{
    __shared__ int s[512];
    int t = threadIdx.x;
    int v = (t < NBLK) ? bsum[t] : 0;
    s[t] = v;
    __syncthreads();
    for (int off = 1; off < 512; off <<= 1) {
        int u = (t >= off) ? s[t - off] : 0;
        __syncthreads();
        s[t] += u;
        __syncthreads();
    }
    bsum[t] = s[t] - v;                      // exclusive block offsets
}

__global__ __launch_bounds__(256) void k_scan3(
    const int* __restrict__ tmp, const int* __restrict__ bsum,
    int* __restrict__ row)
{
    int i = blockIdx.x * 256 + threadIdx.x;
    if (i < NN) row[i] = tmp[i] + bsum[blockIdx.x];
    if (i == 0) row[NN] = NEDGE;
}

__global__ __launch_bounds__(256) void k_fill(
    const int* __restrict__ esrc, const int* __restrict__ edst,
    const int* __restrict__ row, int* __restrict__ cnt, int* __restrict__ adj)
{
    int ei = blockIdx.x * 256 + threadIdx.x;
    if (ei >= NEDGE) return;
    int s, d;
    if (ei < EE) { s = esrc[ei]; d = edst[ei]; } else { s = d = ei - EE; }
    int pos = row[d] + atomicAdd(&cnt[d], 1);
    adj[pos] = s;
}

// ---------- layer 1 GEMM: h1lin = x @ W1 (W1 streamed from L1/L2) ----------
__global__ __launch_bounds__(256) void k_gemm1(
    const float* __restrict__ x, const float* __restrict__ W1,
    const float* __restrict__ a1s, const float* __restrict__ a1d,
    float* __restrict__ h1lin, float* __restrict__ al1s, float* __restrict__ al1d)
{
    __shared__ float sx[4][256];
    const int t = threadIdx.x;
    const int nodeBase = blockIdx.x * 4;

    for (int i = t; i < 4 * 256; i += 256) {
        int r = i >> 8, k = i & 255;
        sx[r][k] = x[(size_t)(nodeBase + r) * FIN + k];
    }
    __syncthreads();

    const int wv = t >> 6;   // node-in-block (one wave per node)
    const int c  = t & 63;   // output column
    const float* wp = W1 + c;
    float acc = 0.f;
    #pragma unroll 8
    for (int k = 0; k < 256; ++k)
        acc += sx[wv][k] * wp[(size_t)k * 64];

    const int n = nodeBase + wv;
    h1lin[(size_t)n * 64 + c] = acc;

    const int h = c >> 3, cc = c & 7;
    float vs = acc * a1s[h * 8 + cc];
    float vd = acc * a1d[h * 8 + cc];
    #pragma unroll
    for (int off = 1; off < 8; off <<= 1) {
        vs += __shfl_xor(vs, off, 64);
        vd += __shfl_xor(vd, off, 64);
    }
    if (cc == 0) { al1s[n * 8 + h] = vs; al1d[n * 8 + h] = vd; }
}

// ---------- layer 1 aggregation: per-dst gather, online softmax, fused ELU ----------
__global__ __launch_bounds__(256) void k_agg1(
    const int* __restrict__ row, const int* __restrict__ adj,
    const float* __restrict__ al1s, const float* __restrict__ al1d,
    const float* __restrict__ h1lin, const float* __restrict__ b1,
    float* __restrict__ h1)
{
    const int wv = threadIdx.x >> 6, lane = threadIdx.x & 63;
    const int n = blockIdx.x * 4 + wv;
    if (n >= NN) return;
    const int h = lane >> 3;
    const float ald = al1d[n * 8 + h];
    const int r0 = row[n], r1 = row[n + 1];

    float m = -1e30f, dsum = 0.f, acc = 0.f;
    int i = r0;
    for (; i + 1 < r1; i += 2) {
        int s0 = adj[i], s1 = adj[i + 1];
        float e0 = lrelu(al1s[s0 * 8 + h] + ald);
        float e1 = lrelu(al1s[s1 * 8 + h] + ald);
        float v0 = h1lin[(size_t)s0 * 64 + lane];
        float v1 = h1lin[(size_t)s1 * 64 + lane];
        float nm = fmaxf(m, fmaxf(e0, e1));
        float sc = __expf(m - nm), w0 = __expf(e0 - nm), w1 = __expf(e1 - nm);
        dsum = dsum * sc + w0 + w1;
        acc  = acc  * sc + w0 * v0 + w1 * v1;
        m = nm;
    }
    if (i < r1) {
        int s0 = adj[i];
        float e0 = lrelu(al1s[s0 * 8 + h] + ald);
        float v0 = h1lin[(size_t)s0 * 64 + lane];
        float nm = fmaxf(m, e0);
        float sc = __expf(m - nm), w0 = __expf(e0 - nm);
        dsum = dsum * sc + w0;
        acc  = acc  * sc + w0 * v0;
        m = nm;
    }
    float v = acc / dsum + b1[lane];
    v = v > 0.f ? v : __expf(v) - 1.f;       // ELU fused
    h1[(size_t)n * 64 + lane] = v;
}

// ---------- layer 2 GEMM: h2 = h1 @ W2, al2s/al2d logits ----------
__global__ __launch_bounds__(256) void k_gemm2(
    const float* __restrict__ h1, const float* __restrict__ W2,
    const float* __restrict__ a2s, const float* __restrict__ a2d,
    float* __restrict__ h2, float* __restrict__ al2s, float* __restrict__ al2d)
{
    __shared__ float sW[64 * 16];
    const int t = threadIdx.x;
    for (int i = t; i < 64 * 16; i += 256) sW[i] = W2[i];
    __syncthreads();
    const int n = blockIdx.x * 16 + (t >> 4);
    const int k = t & 15;
    if (n >= NN) return;
    const float* hr = h1 + (size_t)n * 64;
    float acc = 0.f;
    #pragma unroll
    for (int c = 0; c < 64; ++c) acc += hr[c] * sW[c * 16 + k];
    h2[(size_t)n * 16 + k] = acc;
    float vs = acc * a2s[k], vd = acc * a2d[k];
    #pragma unroll
    for (int off = 1; off < 16; off <<= 1) {
        vs += __shfl_xor(vs, off, 64);
        vd += __shfl_xor(vd, off, 64);
    }
    if (k == 0) { al2s[n] = vs; al2d[n] = vd; }
}

// ---------- layer 2 aggregation + log_softmax ----------
__global__ __launch_bounds__(256) void k_agg2(
    const int* __restrict__ row, const int* __restrict__ adj,
    const float* __restrict__ al2s, const float* __restrict__ al2d,
    const float* __restrict__ h2, const float* __restrict__ b2,
    float* __restrict__ out)
{
    const int wv = threadIdx.x >> 6, lane = threadIdx.x & 63;
    const int n = blockIdx.x * 4 + wv;
    if (n >= NN) return;
    const int k = lane & 15, j = lane >> 4;   // 4 edge-groups x 16 channels
    const float ald = al2d[n];
    const int r0 = row[n], r1 = row[n + 1];

    float m = -1e30f, dsum = 0.f, acc = 0.f;
    for (int i = r0 + j; i < r1; i += 4) {
        int s = adj[i];
        float e = lrelu(al2s[s] + ald);
        float v = h2[(size_t)s * 16 + k];
        float nm = fmaxf(m, e);
        float sc = __expf(m - nm), w = __expf(e - nm);
        dsum = dsum * sc + w;
        acc  = acc  * sc + w * v;
        m = nm;
    }
    // merge the 4 edge-groups (butterfly over j)
    #pragma unroll
    for (int off = 16; off < 64; off <<= 1) {
        float m2 = __shfl_xor(m, off, 64);
        float d2 = __shfl_xor(dsum, off, 64);
        float a2 = __shfl_xor(acc, off, 64);
        float nm = fmaxf(m, m2);
        float s1 = __expf(m - nm), s2 = __expf(m2 - nm);
        dsum = dsum * s1 + d2 * s2;
        acc  = acc  * s1 + a2 * s2;
        m = nm;
    }
    float v = acc / dsum + b2[k];
    // log_softmax over the 16 channels (within j-group of 16 lanes)
    float mx = v;
    #pragma unroll
    for (int off = 1; off < 16; off <<= 1) mx = fmaxf(mx, __shfl_xor(mx, off, 64));
    float se = __expf(v - mx);
    #pragma unroll
    for (int off = 1; off < 16; off <<= 1) se += __shfl_xor(se, off, 64);
    float ls = mx + __logf(se);
    if (j == 0) out[(size_t)n * 16 + k] = v - ls;
}

extern "C" void kernel_launch(void* const* d_in, const int* in_sizes, int n_in,
                              void* d_out, int out_size, void* d_ws, size_t ws_size,
                              hipStream_t stream)
{
    const float* x    = (const float*)d_in[0];
    const int*   eidx = (const int*)d_in[1];
    const float* W1   = (const float*)d_in[2];
    const float* a1s  = (const float*)d_in[3];
    const float* a1d  = (const float*)d_in[4];
    const float* b1   = (const float*)d_in[5];
    const float* W2   = (const float*)d_in[6];
    const float* a2s  = (const float*)d_in[7];
    const float* a2d  = (const float*)d_in[8];
    const float* b2   = (const float*)d_in[9];
    float* out = (float*)d_out;
    float* ws  = (float*)d_ws;

    const int* esrc = eidx;
    const int* edst = eidx + EE;

    int* deg  = (int*)(ws + OFF_DEG);
    int* cnt  = (int*)(ws + OFF_CNT);
    int* row  = (int*)(ws + OFF_ROW);
    int* tmp  = (int*)(ws + OFF_TMP);
    int* bsum = (int*)(ws + OFF_BSUM);
    int* adj  = (int*)(ws + OFF_ADJ);
    float* h1lin = ws + OFF_H1LIN;
    float* al1s  = ws + OFF_AL1S;
    float* al1d  = ws + OFF_AL1D;
    float* h1    = ws + OFF_H1;
    float* h2    = ws + OFF_H2;
    float* al2s  = ws + OFF_AL2S;
    float* al2d  = ws + OFF_AL2D;

    hipMemsetAsync(ws, 0, (size_t)NZERO_I * sizeof(int), stream);

    const int gE = (NEDGE + 255) / 256;
    k_hist <<<gE,   256, 0, stream>>>(edst, deg);
    k_scan1<<<NBLK, 256, 0, stream>>>(deg, tmp, bsum);
    k_scan2<<<1,    512, 0, stream>>>(bsum);
    k_scan3<<<NBLK, 256, 0, stream>>>(tmp, bsum, row);
    k_fill <<<gE,   256, 0, stream>>>(esrc, edst, row, cnt, adj);

    k_gemm1<<<NN / 4, 256, 0, stream>>>(x, W1, a1s, a1d, h1lin, al1s, al1d);
    k_agg1 <<<NN / 4, 256, 0, stream>>>(row, adj, al1s, al1d, h1lin, b1, h1);
    k_gemm2<<<NN / 16, 256, 0, stream>>>(h1, W2, a2s, a2d, h2, al2s, al2d);
    k_agg2 <<<NN / 4, 256, 0, stream>>>(row, adj, al2s, al2d, h2, b2, out);
}

// Round 3
// 537.109 us; speedup vs baseline: 7.0878x; 1.3446x over previous
//
#include <hip/hip_runtime.h>
#include <math.h>

#define NN   100000
#define EE   1600000
#define FIN  256
#define NCLS 16
#define NEG  0.2f

#define NEDGE (EE + NN)   // with self-loops
#define NBLK  ((NN + 255) / 256)   // 391 scan blocks

// ---- workspace layout (4-byte element offsets) ----
#define OFF_DEG   0                    // [NN] int, zeroed
#define OFF_CNT   (NN)                 // [NN] int, zeroed
#define NZERO_I   (2*NN)
#define OFF_ROW   (2*NN)               // [NN+1] int
#define OFF_TMP   (3*NN + 4)           // [NN] int
#define OFF_BSUM  (4*NN + 8)           // [512] int
#define OFF_ADJ   (4*NN + 520)         // [NEDGE] int (src per slot, CSR by dst)
#define OFF_H1LIN (OFF_ADJ + NEDGE)    // [NN*64]
#define OFF_AL1S  (OFF_H1LIN + NN*64)  // [NN*8]
#define OFF_AL1D  (OFF_AL1S + NN*8)    // [NN*8]
#define OFF_H1    (OFF_AL1D + NN*8)    // [NN*64]
#define OFF_H2    (OFF_H1 + NN*64)     // [NN*16]
#define OFF_AL2S  (OFF_H2 + NN*16)     // [NN]
#define OFF_AL2D  (OFF_AL2S + NN)      // [NN]

__device__ __forceinline__ float lrelu(float x) { return x >= 0.f ? x : NEG * x; }

// ---------- CSR build ----------
__global__ __launch_bounds__(256) void k_hist(
    const int* __restrict__ edst, int* __restrict__ deg)
{
    int ei = blockIdx.x * 256 + threadIdx.x;
    if (ei >= NEDGE) return;
    int d = (ei < EE) ? edst[ei] : ei - EE;
    atomicAdd(&deg[d], 1);
}

__global__ __launch_bounds__(256) void k_scan1(
    const int* __restrict__ deg, int* __restrict__ tmp, int* __restrict__ bsum)
{
    __shared__ int s[256];
    int t = threadIdx.x;
    int i = blockIdx.x * 256 + t;
    int v = (i < NN) ? deg[i] : 0;
    s[t] = v;
    __syncthreads();
    for (int off = 1; off < 256; off <<= 1) {
        int u = (t >= off) ? s[t - off] : 0;
        __syncthreads();
        s[t] += u;
        __syncthreads();
    }
    if (i < NN) tmp[i] = s[t] - v;          // exclusive within block
    if (t == 255) bsum[blockIdx.x] = s[255]; // block total
}

__global__ __launch_bounds__(512) void k_scan2(int* __restrict__ bsum)
{
    __shared__ int s[512];
    int t = threadIdx.x;
    int v = (t < NBLK) ? bsum[t] : 0;
    s[t] = v;
    __syncthreads();
    for (int off = 1; off < 512; off <<= 1) {
        int u = (t >= off) ? s[t - off] : 0;
        __syncthreads();
        s[t] += u;
        __syncthreads();
    }
    bsum[t] = s[t] - v;                      // exclusive block offsets
}

__global__ __launch_bounds__(256) void k_scan3(
    const int* __restrict__ tmp, const int* __restrict__ bsum,
    int* __restrict__ row)
{
    int i = blockIdx.x * 256 + threadIdx.x;
    if (i < NN) row[i] = tmp[i] + bsum[blockIdx.x];
    if (i == 0) row[NN] = NEDGE;
}

__global__ __launch_bounds__(256) void k_fill(
    const int* __restrict__ esrc, const int* __restrict__ edst,
    const int* __restrict__ row, int* __restrict__ cnt, int* __restrict__ adj)
{
    int ei = blockIdx.x * 256 + threadIdx.x;
    if (ei >= NEDGE) return;
    int s, d;
    if (ei < EE) { s = esrc[ei]; d = edst[ei]; } else { s = d = ei - EE; }
    int pos = row[d] + atomicAdd(&cnt[d], 1);
    adj[pos] = s;
}

// ---------- layer 1 GEMM: 64x64 block tile, 4x4 register tile ----------
// h1lin = x @ W1; fused per-head logit reductions in epilogue.
__global__ __launch_bounds__(256) void k_gemm1(
    const float* __restrict__ x, const float* __restrict__ W1,
    const float* __restrict__ a1s, const float* __restrict__ a1d,
    float* __restrict__ h1lin, float* __restrict__ al1s, float* __restrict__ al1d)
{
    __shared__ float sxT[32][68];   // x tile transposed [k][node], pad 68 (16B-aligned rows)
    __shared__ float sW[32][64];    // W1 chunk [k][col]
    const int t = threadIdx.x;
    const int n0 = blockIdx.x * 64;
    const int tr = t >> 4, tc = t & 15;   // 16 node-groups x 16 col-groups

    float acc[4][4] = {};

    for (int kc = 0; kc < 256; kc += 32) {
        __syncthreads();   // previous chunk's reads done
        #pragma unroll
        for (int it = 0; it < 2; ++it) {
            int i = t + it * 256;
            int r = i >> 3, fj = i & 7;          // row in tile, float4 index
            int n = n0 + r;
            float4 v = (n < NN) ? *(const float4*)(x + (size_t)n * FIN + kc + fj * 4)
                                : make_float4(0.f, 0.f, 0.f, 0.f);
            sxT[fj * 4 + 0][r] = v.x;
            sxT[fj * 4 + 1][r] = v.y;
            sxT[fj * 4 + 2][r] = v.z;
            sxT[fj * 4 + 3][r] = v.w;
        }
        #pragma unroll
        for (int it = 0; it < 2; ++it) {
            int i = t + it * 256;
            int r = i >> 4, fj = i & 15;
            *(float4*)&sW[r][fj * 4] = *(const float4*)(W1 + (size_t)(kc + r) * 64 + fj * 4);
        }
        __syncthreads();
        #pragma unroll
        for (int k = 0; k < 32; ++k) {
            float4 a = *(const float4*)&sxT[k][tr * 4];
            float4 b = *(const float4*)&sW[k][tc * 4];
            acc[0][0] += a.x * b.x; acc[0][1] += a.x * b.y; acc[0][2] += a.x * b.z; acc[0][3] += a.x * b.w;
            acc[1][0] += a.y * b.x; acc[1][1] += a.y * b.y; acc[1][2] += a.y * b.z; acc[1][3] += a.y * b.w;
            acc[2][0] += a.z * b.x; acc[2][1] += a.z * b.y; acc[2][2] += a.z * b.z; acc[2][3] += a.z * b.w;
            acc[3][0] += a.w * b.x; acc[3][1] += a.w * b.y; acc[3][2] += a.w * b.z; acc[3][3] += a.w * b.w;
        }
    }

    // store h1lin (columns 4tc..4tc+3 of nodes n0+4tr..+3)
    #pragma unroll
    for (int j = 0; j < 4; ++j) {
        int n = n0 + tr * 4 + j;
        if (n < NN) {
            float4 v = make_float4(acc[j][0], acc[j][1], acc[j][2], acc[j][3]);
            *(float4*)(h1lin + (size_t)n * 64 + tc * 4) = v;
        }
    }

    // fused logits: a1s/a1d flat over 64 cols; head = tc>>1
    float sa[4], da[4];
    #pragma unroll
    for (int u = 0; u < 4; ++u) { sa[u] = a1s[tc * 4 + u]; da[u] = a1d[tc * 4 + u]; }
    #pragma unroll
    for (int j = 0; j < 4; ++j) {
        float vs = acc[j][0] * sa[0] + acc[j][1] * sa[1] + acc[j][2] * sa[2] + acc[j][3] * sa[3];
        float vd = acc[j][0] * da[0] + acc[j][1] * da[1] + acc[j][2] * da[2] + acc[j][3] * da[3];
        vs += __shfl_xor(vs, 1, 64);
        vd += __shfl_xor(vd, 1, 64);
        int n = n0 + tr * 4 + j;
        if (!(tc & 1) && n < NN) {
            al1s[n * 8 + (tc >> 1)] = vs;
            al1d[n * 8 + (tc >> 1)] = vd;
        }
    }
}

// ---------- layer 1 aggregation: per-dst gather, online softmax, fused ELU ----------
__global__ __launch_bounds__(256) void k_agg1(
    const int* __restrict__ row, const int* __restrict__ adj,
    const float* __restrict__ al1s, const float* __restrict__ al1d,
    const float* __restrict__ h1lin, const float* __restrict__ b1,
    float* __restrict__ h1)
{
    const int wv = threadIdx.x >> 6, lane = threadIdx.x & 63;
    const int n = blockIdx.x * 4 + wv;
    if (n >= NN) return;
    const int h = lane >> 3;
    const float ald = al1d[n * 8 + h];
    const int r0 = row[n], r1 = row[n + 1];

    float m = -1e30f, dsum = 0.f, acc = 0.f;
    int i = r0;
    for (; i + 1 < r1; i += 2) {
        int s0 = adj[i], s1 = adj[i + 1];
        float e0 = lrelu(al1s[s0 * 8 + h] + ald);
        float e1 = lrelu(al1s[s1 * 8 + h] + ald);
        float v0 = h1lin[(size_t)s0 * 64 + lane];
        float v1 = h1lin[(size_t)s1 * 64 + lane];
        float nm = fmaxf(m, fmaxf(e0, e1));
        float sc = __expf(m - nm), w0 = __expf(e0 - nm), w1 = __expf(e1 - nm);
        dsum = dsum * sc + w0 + w1;
        acc  = acc  * sc + w0 * v0 + w1 * v1;
        m = nm;
    }
    if (i < r1) {
        int s0 = adj[i];
        float e0 = lrelu(al1s[s0 * 8 + h] + ald);
        float v0 = h1lin[(size_t)s0 * 64 + lane];
        float nm = fmaxf(m, e0);
        float sc = __expf(m - nm), w0 = __expf(e0 - nm);
        dsum = dsum * sc + w0;
        acc  = acc  * sc + w0 * v0;
        m = nm;
    }
    float v = acc / dsum + b1[lane];
    v = v > 0.f ? v : __expf(v) - 1.f;       // ELU fused
    h1[(size_t)n * 64 + lane] = v;
}

// ---------- layer 2 GEMM: h2 = h1 @ W2, al2s/al2d logits ----------
__global__ __launch_bounds__(256) void k_gemm2(
    const float* __restrict__ h1, const float* __restrict__ W2,
    const float* __restrict__ a2s, const float* __restrict__ a2d,
    float* __restrict__ h2, float* __restrict__ al2s, float* __restrict__ al2d)
{
    __shared__ float sW[64 * 16];
    const int t = threadIdx.x;
    for (int i = t; i < 64 * 16; i += 256) sW[i] = W2[i];
    __syncthreads();
    const int n = blockIdx.x * 16 + (t >> 4);
    const int k = t & 15;
    if (n >= NN) return;
    const float* hr = h1 + (size_t)n * 64;
    float acc = 0.f;
    #pragma unroll
    for (int c = 0; c < 64; ++c) acc += hr[c] * sW[c * 16 + k];
    h2[(size_t)n * 16 + k] = acc;
    float vs = acc * a2s[k], vd = acc * a2d[k];
    #pragma unroll
    for (int off = 1; off < 16; off <<= 1) {
        vs += __shfl_xor(vs, off, 64);
        vd += __shfl_xor(vd, off, 64);
    }
    if (k == 0) { al2s[n] = vs; al2d[n] = vd; }
}

// ---------- layer 2 aggregation + log_softmax ----------
__global__ __launch_bounds__(256) void k_agg2(
    const int* __restrict__ row, const int* __restrict__ adj,
    const float* __restrict__ al2s, const float* __restrict__ al2d,
    const float* __restrict__ h2, const float* __restrict__ b2,
    float* __restrict__ out)
{
    const int wv = threadIdx.x >> 6, lane = threadIdx.x & 63;
    const int n = blockIdx.x * 4 + wv;
    if (n >= NN) return;
    const int k = lane & 15, j = lane >> 4;   // 4 edge-groups x 16 channels
    const float ald = al2d[n];
    const int r0 = row[n], r1 = row[n + 1];

    float m = -1e30f, dsum = 0.f, acc = 0.f;
    for (int i = r0 + j; i < r1; i += 4) {
        int s = adj[i];
        float e = lrelu(al2s[s] + ald);
        float v = h2[(size_t)s * 16 + k];
        float nm = fmaxf(m, e);
        float sc = __expf(m - nm), w = __expf(e - nm);
        dsum = dsum * sc + w;
        acc  = acc  * sc + w * v;
        m = nm;
    }
    #pragma unroll
    for (int off = 16; off < 64; off <<= 1) {
        float m2 = __shfl_xor(m, off, 64);
        float d2 = __shfl_xor(dsum, off, 64);
        float a2 = __shfl_xor(acc, off, 64);
        float nm = fmaxf(m, m2);
        float s1 = __expf(m - nm), s2 = __expf(m2 - nm);
        dsum = dsum * s1 + d2 * s2;
        acc  = acc  * s1 + a2 * s2;
        m = nm;
    }
    float v = acc / dsum + b2[k];
    float mx = v;
    #pragma unroll
    for (int off = 1; off < 16; off <<= 1) mx = fmaxf(mx, __shfl_xor(mx, off, 64));
    float se = __expf(v - mx);
    #pragma unroll
    for (int off = 1; off < 16; off <<= 1) se += __shfl_xor(se, off, 64);
    float ls = mx + __logf(se);
    if (j == 0) out[(size_t)n * 16 + k] = v - ls;
}

extern "C" void kernel_launch(void* const* d_in, const int* in_sizes, int n_in,
                              void* d_out, int out_size, void* d_ws, size_t ws_size,
                              hipStream_t stream)
{
    const float* x    = (const float*)d_in[0];
    const int*   eidx = (const int*)d_in[1];
    const float* W1   = (const float*)d_in[2];
    const float* a1s  = (const float*)d_in[3];
    const float* a1d  = (const float*)d_in[4];
    const float* b1   = (const float*)d_in[5];
    const float* W2   = (const float*)d_in[6];
    const float* a2s  = (const float*)d_in[7];
    const float* a2d  = (const float*)d_in[8];
    const float* b2   = (const float*)d_in[9];
    float* out = (float*)d_out;
    float* ws  = (float*)d_ws;

    const int* esrc = eidx;
    const int* edst = eidx + EE;

    int* deg  = (int*)(ws + OFF_DEG);
    int* cnt  = (int*)(ws + OFF_CNT);
    int* row  = (int*)(ws + OFF_ROW);
    int* tmp  = (int*)(ws + OFF_TMP);
    int* bsum = (int*)(ws + OFF_BSUM);
    int* adj  = (int*)(ws + OFF_ADJ);
    float* h1lin = ws + OFF_H1LIN;
    float* al1s  = ws + OFF_AL1S;
    float* al1d  = ws + OFF_AL1D;
    float* h1    = ws + OFF_H1;
    float* h2    = ws + OFF_H2;
    float* al2s  = ws + OFF_AL2S;
    float* al2d  = ws + OFF_AL2D;

    hipMemsetAsync(ws, 0, (size_t)NZERO_I * sizeof(int), stream);

    const int gE = (NEDGE + 255) / 256;
    k_hist <<<gE,   256, 0, stream>>>(edst, deg);
    k_scan1<<<NBLK, 256, 0, stream>>>(deg, tmp, bsum);
    k_scan2<<<1,    512, 0, stream>>>(bsum);
    k_scan3<<<NBLK, 256, 0, stream>>>(tmp, bsum, row);
    k_fill <<<gE,   256, 0, stream>>>(esrc, edst, row, cnt, adj);

    k_gemm1<<<(NN + 63) / 64, 256, 0, stream>>>(x, W1, a1s, a1d, h1lin, al1s, al1d);
    k_agg1 <<<NN / 4, 256, 0, stream>>>(row, adj, al1s, al1d, h1lin, b1, h1);
    k_gemm2<<<NN / 16, 256, 0, stream>>>(h1, W2, a2s, a2d, h2, al2s, al2d);
    k_agg2 <<<NN / 4, 256, 0, stream>>>(row, adj, al2s, al2d, h2, b2, out);
}